// Round 1
// 85.645 us; speedup vs baseline: 1.1458x; 1.1458x over previous
//
#include <hip/hip_runtime.h>
#include <math.h>

#define N_TOTAL 8192
#define BHALF   4096
#define KDIM    128
#define NTILE   64          // 8192 / 128 tile grid
#define NTRI    2080        // 64*65/2 triangular tiles
#define NBLK_PW 512         // persistent blocks, exactly 2 per CU

typedef __bf16 bf16x8 __attribute__((ext_vector_type(8)));
typedef __bf16 bf16x2 __attribute__((ext_vector_type(2)));
typedef float  f32x4  __attribute__((ext_vector_type(4)));

// async global->LDS, 16B per lane; LDS dest must be lane-contiguous.
#define GLOAD_LDS16(GSRC, LDST)                                                \
    __builtin_amdgcn_global_load_lds(                                          \
        (const __attribute__((address_space(1))) void*)(GSRC),                 \
        (__attribute__((address_space(3))) void*)(LDST), 16, 0, 0)

// ---------------------------------------------------------------------------
// Kernel A (fused prep+pos): one wave per pair (i, i+BHALF).
//  - fp32 sq-norms for both rows (exact), bf16 copy of both rows,
//  - positive-pair term written to posPart[block] (no atomics),
//  - block 0 zeroes out[0] (replaces the hipMemsetAsync dispatch).
// ---------------------------------------------------------------------------
__global__ __launch_bounds__(256) void k_prep_pos(const float* __restrict__ F,
                                                  __bf16* __restrict__ Fbf,
                                                  float* __restrict__ sq,
                                                  float* __restrict__ posPart,
                                                  float* __restrict__ out) {
    int t = threadIdx.x;
    int w = t >> 6, l = t & 63;
    int p = blockIdx.x * 4 + w;          // pair index 0..4095
    const float2* r1 = (const float2*)(F + (size_t)p * KDIM);
    const float2* r2 = (const float2*)(F + (size_t)(p + BHALF) * KDIM);
    float2 a = r1[l];
    float2 c = r2[l];

    float s1 = fmaf(a.x, a.x, a.y * a.y);
    float s2 = fmaf(c.x, c.x, c.y * c.y);
    float dp = fmaf(a.x, c.x, a.y * c.y);
#pragma unroll
    for (int off = 32; off > 0; off >>= 1) {
        s1 += __shfl_down(s1, off);
        s2 += __shfl_down(s2, off);
        dp += __shfl_down(dp, off);
    }

    bf16x2 pa, pc;
    pa[0] = (__bf16)a.x; pa[1] = (__bf16)a.y;
    pc[0] = (__bf16)c.x; pc[1] = (__bf16)c.y;
    ((bf16x2*)(Fbf + (size_t)p * KDIM))[l] = pa;
    ((bf16x2*)(Fbf + (size_t)(p + BHALF) * KDIM))[l] = pc;

    __shared__ float posRed[4];
    if (l == 0) {
        sq[p] = s1;
        sq[p + BHALF] = s2;
        float d2 = fmaxf(s1 + s2 - 2.0f * dp, 0.0f);
        posRed[w] = logf(1.0f + d2);
    }
    __syncthreads();
    if (t == 0) {
        posPart[blockIdx.x] = posRed[0] + posRed[1] + posRed[2] + posRed[3];
        if (blockIdx.x == 0) out[0] = 0.0f;
    }
}

// ---------------------------------------------------------------------------
// Kernel B: MFMA pairwise Cauchy row/col sums, 128x128 tiles.
// 512 persistent blocks; block b owns a CONTIGUOUS chunk of 4-5 triangular
// tiles (row-major in (ti,tj)). A panel is re-staged only when ti changes;
// diagonal tiles read the B operand straight from the A panel (no B stage).
// NO atomics: tile (ti,tj) writes row sums to Tpart[tj][I..I+127] and col
// sums to Tpart[ti][J..J+127] — each (slot, element) written exactly once.
// 16-B-granule XOR swizzle on the GLOBAL side of global_load_lds keeps the
// fragment ds_read_b128s conflict-free (2-way max = free).
// ---------------------------------------------------------------------------
__global__ __launch_bounds__(512, 4) void k_pairwise(
        const __bf16* __restrict__ Fbf,
        const float* __restrict__ sq,
        float* __restrict__ Tpart) {
    __shared__ __align__(16) __bf16 As[128 * 128];
    __shared__ __align__(16) __bf16 Bs[128 * 128];
    __shared__ float rowAcc[128][2];
    __shared__ float colAcc[128][4];

    int t = threadIdx.x;
    int w = t >> 6;              // wave 0..7
    int l = t & 63;
    int wr = w >> 1, wc = w & 1; // 4x2 wave grid
    int low = l & 15, kb = l >> 4;

    // ---- contiguous chunk assignment: blocks 0..31 get 5 tiles, rest 4 ----
    int bid = blockIdx.x;
    int start = bid * 4 + (bid < 32 ? bid : 32);
    int cnt = (bid < 32) ? 5 : 4;

    // decode start -> (ti, tj), then advance incrementally
    int ti = (int)floorf((129.0f - sqrtf(16641.0f - 8.0f * (float)start)) * 0.5f);
    while (ti * (129 - ti) / 2 > start) --ti;
    while ((ti + 1) * (128 - ti) / 2 <= start) ++ti;
    int tj = ti + (start - ti * (129 - ti) / 2);

    int curTi = -1;
#pragma unroll 1
    for (int n = 0; n < cnt; ++n) {
        int I = ti * 128, J = tj * 128;
        bool diag = (ti == tj);

        // ---- stage tiles (2048 granules each); skip A if panel unchanged ----
        if (ti != curTi) {
            const __bf16* FA = Fbf + (size_t)I * KDIM;
#pragma unroll
            for (int it = 0; it < 4; ++it) {
                int f = it * 512 + t;            // granule slot 0..2047
                int row = f >> 4;
                int sg = f & 15;
                int g = sg ^ (row & 15);         // global granule landing here
                GLOAD_LDS16(FA + row * KDIM + g * 8, As + (size_t)f * 8);
            }
            curTi = ti;
        }
        if (!diag) {
            const __bf16* FB = Fbf + (size_t)J * KDIM;
#pragma unroll
            for (int it = 0; it < 4; ++it) {
                int f = it * 512 + t;
                int row = f >> 4;
                int sg = f & 15;
                int g = sg ^ (row & 15);
                GLOAD_LDS16(FB + row * KDIM + g * 8, Bs + (size_t)f * 8);
            }
        }
        __syncthreads();

        // ---- MFMA K-loop: 4 steps of K=32, 2x4 fragments per wave ----
        const bf16x8* Asg = (const bf16x8*)As;
        const bf16x8* Bsg = diag ? (const bf16x8*)As : (const bf16x8*)Bs;
        f32x4 acc[2][4] = {};
#pragma unroll
        for (int s = 0; s < 4; ++s) {
            int g = s * 4 + kb;
            bf16x8 aF[2], bF[4];
#pragma unroll
            for (int fr = 0; fr < 2; ++fr) {
                int R = wr * 32 + fr * 16 + low;
                aF[fr] = Asg[R * 16 + (g ^ low)];
            }
#pragma unroll
            for (int fc = 0; fc < 4; ++fc) {
                int C = wc * 64 + fc * 16 + low;
                bF[fc] = Bsg[C * 16 + (g ^ low)];
            }
#pragma unroll
            for (int fr = 0; fr < 2; ++fr)
#pragma unroll
                for (int fc = 0; fc < 4; ++fc)
                    acc[fr][fc] = __builtin_amdgcn_mfma_f32_16x16x32_bf16(
                        aF[fr], bF[fc], acc[fr][fc], 0, 0, 0);
        }

        // ---- epilogue: Cauchy + row/col partial sums ----
        // C/D layout: col = low, row = kb*4 + reg (within each 16x16 frag)
        float sqi[2][4], sqj[4];
#pragma unroll
        for (int fr = 0; fr < 2; ++fr)
#pragma unroll
            for (int r = 0; r < 4; ++r)
                sqi[fr][r] = sq[I + wr * 32 + fr * 16 + kb * 4 + r];
#pragma unroll
        for (int fc = 0; fc < 4; ++fc)
            sqj[fc] = sq[J + wc * 64 + fc * 16 + low];

        float rowPart[2][4] = {};
        float colPart[4] = {0.f, 0.f, 0.f, 0.f};
#pragma unroll
        for (int fr = 0; fr < 2; ++fr) {
#pragma unroll
            for (int fc = 0; fc < 4; ++fc) {
#pragma unroll
                for (int r = 0; r < 4; ++r) {
                    float d2 = sqi[fr][r] + sqj[fc] - 2.0f * acc[fr][fc][r];
                    d2 = fmaxf(d2, 0.0f);
                    float v = __builtin_amdgcn_rcpf(1.0f + d2);
                    rowPart[fr][r] += v;
                    colPart[fc] += v;
                }
            }
        }

        // row partials: reduce across the 16 lanes sharing a row (low)
#pragma unroll
        for (int fr = 0; fr < 2; ++fr)
#pragma unroll
            for (int r = 0; r < 4; ++r) {
                float x = rowPart[fr][r];
                x += __shfl_xor(x, 1);
                x += __shfl_xor(x, 2);
                x += __shfl_xor(x, 4);
                x += __shfl_xor(x, 8);
                if (low == 0)
                    rowAcc[wr * 32 + fr * 16 + kb * 4 + r][wc] = x;
            }

        // col partials: reduce across the 4 lane-quads (kb)
#pragma unroll
        for (int fc = 0; fc < 4; ++fc) {
            float x = colPart[fc];
            x += __shfl_xor(x, 16);
            x += __shfl_xor(x, 32);
            if (kb == 0)
                colAcc[wc * 64 + fc * 16 + low][wr] = x;
        }
        __syncthreads();

        // deterministic scatter instead of atomics:
        // slot tj holds row-contribs of panel ti; slot ti holds col-contribs
        // of panel tj. For any element, slots 0..63 are each written once.
        if (t < 128) {
            Tpart[tj * N_TOTAL + I + t] = rowAcc[t][0] + rowAcc[t][1];
        } else if (t < 256 && !diag) {
            int c = t - 128;
            Tpart[ti * N_TOTAL + J + c] =
                colAcc[c][0] + colAcc[c][1] + colAcc[c][2] + colAcc[c][3];
        }

        // advance to next triangular tile
        ++tj;
        if (tj == NTILE) { ++ti; tj = ti; }
    }
}

// ---------------------------------------------------------------------------
// Kernel C: neg term. 32 blocks x 256 threads; thread i column-reduces the
// 64 Tpart slots (fully coalesced), takes log(T-1); lanes <32 also fold the
// pos partials; block-reduce; one atomicAdd into out per block (32 total).
// ---------------------------------------------------------------------------
__global__ __launch_bounds__(256) void k_final(const float* __restrict__ Tpart,
                                               const float* __restrict__ posPart,
                                               float* __restrict__ out) {
    int t = threadIdx.x;
    int i = blockIdx.x * 256 + t;
    float s = 0.0f;
#pragma unroll 8
    for (int k = 0; k < NTILE; ++k) s += Tpart[k * N_TOTAL + i];
    float v = logf(s - 1.0f);
    if (t < 32) v += 2.0f * posPart[blockIdx.x * 32 + t];  // *2 cancels /(2b)
#pragma unroll
    for (int off = 32; off > 0; off >>= 1) v += __shfl_down(v, off);
    __shared__ float red[4];
    int w = t >> 6, l = t & 63;
    if (l == 0) red[w] = v;
    __syncthreads();
    if (t == 0) {
        float S = red[0] + red[1] + red[2] + red[3];
        atomicAdd(out, S * (1.0f / (2.0f * (float)BHALF)));
    }
}

// ---------------------------------------------------------------------------
extern "C" void kernel_launch(void* const* d_in, const int* in_sizes, int n_in,
                              void* d_out, int out_size, void* d_ws, size_t ws_size,
                              hipStream_t stream) {
    const float* F = (const float*)d_in[0];
    float* out = (float*)d_out;

    char* ws = (char*)d_ws;
    __bf16* Fbf    = (__bf16*)ws;                                 // 2 MB
    float*  sq     = (float*)(ws + (size_t)N_TOTAL * KDIM * 2);   // 32 KB
    float*  posPart = sq + N_TOTAL;                               // 4 KB
    float*  Tpart  = posPart + 1024;                              // 2 MB

    k_prep_pos<<<BHALF / 4, 256, 0, stream>>>(F, Fbf, sq, posPart, out);
    k_pairwise<<<NBLK_PW, 512, 0, stream>>>(Fbf, sq, Tpart);
    k_final<<<N_TOTAL / 256, 256, 0, stream>>>(Tpart, posPart, out);
}